// Round 3
// baseline (521.636 us; speedup 1.0000x reference)
//
#include <hip/hip_runtime.h>
#include <math.h>

// MEASUREMENT ROUND: identical kernel to R2, launched 5x back-to-back
// (idempotent). kernel_time = (dur_us - 339)/4. The per-dispatch duration is
// masked in the top-5 rocprof view by the harness's ~160us 1GB ws-poison
// fills; this isolates it.
//
// out[b*K+k] = tanh( dot(x[b,k,:], W[k,:]) ), B=64, K=4096, N=256.
constexpr int GK = 4096;
constexpr int GN = 256;
constexpr int ROWS_PER_WAVE = 16;

typedef float f32x4 __attribute__((ext_vector_type(4)));

__global__ __launch_bounds__(256) void ginn_input_layer(
    const float* __restrict__ x,   // [B*K, N]
    const float* __restrict__ W,   // [K, N]
    float* __restrict__ out)       // [B*K]
{
    const int lane   = threadIdx.x & 63;
    const int waveId = (int)((blockIdx.x * blockDim.x + threadIdx.x) >> 6);
    const long long row0 = (long long)waveId * ROWS_PER_WAVE;
    const int k0 = (int)(row0 & (GK - 1));   // 16-row window stays within one b

    const f32x4* xp = (const f32x4*)(x + row0 * GN) + lane;
    const f32x4* wp = (const f32x4*)(W + (long long)k0 * GN) + lane;

    #pragma unroll
    for (int rb = 0; rb < ROWS_PER_WAVE; rb += 4) {
        f32x4 xv[4], wv[4];
        #pragma unroll
        for (int j = 0; j < 4; ++j) {
            xv[j] = __builtin_nontemporal_load(xp + (long long)(rb + j) * (GN / 4));
            wv[j] = wp[(long long)(rb + j) * (GN / 4)];
        }
        float s[4];
        #pragma unroll
        for (int j = 0; j < 4; ++j) {
            s[j] = fmaf(xv[j].x, wv[j].x,
                   fmaf(xv[j].y, wv[j].y,
                   fmaf(xv[j].z, wv[j].z, xv[j].w * wv[j].w)));
        }
        #pragma unroll
        for (int off = 32; off > 0; off >>= 1) {
            #pragma unroll
            for (int j = 0; j < 4; ++j)
                s[j] += __shfl_xor(s[j], off, 64);
        }
        if (lane == 0) {
            f32x4 o;
            o.x = tanhf(s[0]); o.y = tanhf(s[1]);
            o.z = tanhf(s[2]); o.w = tanhf(s[3]);
            *(f32x4*)(out + row0 + rb) = o;
        }
    }
}

extern "C" void kernel_launch(void* const* d_in, const int* in_sizes, int n_in,
                              void* d_out, int out_size, void* d_ws, size_t ws_size,
                              hipStream_t stream) {
    const float* x = (const float*)d_in[0];   // [B,K,N] fp32
    const float* W = (const float*)d_in[1];   // [K,N]   fp32
    float* out = (float*)d_out;               // [B,K]   fp32

    const int blocks = out_size / (4 * ROWS_PER_WAVE);   // 262144/64 = 4096

    // 5 idempotent launches: Delta(dur_us)/4 = true per-launch kernel time.
    #pragma unroll
    for (int rep = 0; rep < 5; ++rep)
        ginn_input_layer<<<blocks, 256, 0, stream>>>(x, W, out);
}

// Round 4
// 336.871 us; speedup vs baseline: 1.5485x; 1.5485x over previous
//
#include <hip/hip_runtime.h>
#include <math.h>

// FINAL (revert of R3's 5x-launch measurement scaffold to single launch).
//
// out[b*K+k] = tanh( dot(x[b,k,:], W[k,:]) ), B=64, K=4096, N=256.
// Pure HBM-bandwidth problem: x = 256 MiB streamed once, W = 4 MiB (L2-hot),
// out = 1 MiB. Measured kernel time (R3 5x-launch delta): 45.7 us for 274 MB
// => ~6.0 TB/s effective, 90-95% of the 6.3-6.65 TB/s achievable ceiling.
//
// Structure: one wave per row (64 lanes x float4 = 256 floats = one row,
// fully coalesced 1 KiB/wave loads). 16 consecutive rows per wave, processed
// 4 at a time for ILP (8 float4 loads in flight/lane). Nontemporal hint on x
// (streamed once, 256 MiB = L3-sized; keep it from evicting L2-hot W).
constexpr int GK = 4096;
constexpr int GN = 256;
constexpr int ROWS_PER_WAVE = 16;

typedef float f32x4 __attribute__((ext_vector_type(4)));

__global__ __launch_bounds__(256) void ginn_input_layer(
    const float* __restrict__ x,   // [B*K, N]
    const float* __restrict__ W,   // [K, N]
    float* __restrict__ out)       // [B*K]
{
    const int lane   = threadIdx.x & 63;
    const int waveId = (int)((blockIdx.x * blockDim.x + threadIdx.x) >> 6);
    const long long row0 = (long long)waveId * ROWS_PER_WAVE;
    const int k0 = (int)(row0 & (GK - 1));   // 16-row window stays within one b

    const f32x4* xp = (const f32x4*)(x + row0 * GN) + lane;
    const f32x4* wp = (const f32x4*)(W + (long long)k0 * GN) + lane;

    #pragma unroll
    for (int rb = 0; rb < ROWS_PER_WAVE; rb += 4) {
        f32x4 xv[4], wv[4];
        #pragma unroll
        for (int j = 0; j < 4; ++j) {
            xv[j] = __builtin_nontemporal_load(xp + (long long)(rb + j) * (GN / 4));
            wv[j] = wp[(long long)(rb + j) * (GN / 4)];
        }
        float s[4];
        #pragma unroll
        for (int j = 0; j < 4; ++j) {
            s[j] = fmaf(xv[j].x, wv[j].x,
                   fmaf(xv[j].y, wv[j].y,
                   fmaf(xv[j].z, wv[j].z, xv[j].w * wv[j].w)));
        }
        // 4 independent butterfly reductions interleave across the 6 steps
        #pragma unroll
        for (int off = 32; off > 0; off >>= 1) {
            #pragma unroll
            for (int j = 0; j < 4; ++j)
                s[j] += __shfl_xor(s[j], off, 64);
        }
        if (lane == 0) {
            f32x4 o;
            o.x = tanhf(s[0]); o.y = tanhf(s[1]);
            o.z = tanhf(s[2]); o.w = tanhf(s[3]);
            *(f32x4*)(out + row0 + rb) = o;   // row0+rb % 4 == 0 -> aligned
        }
    }
}

extern "C" void kernel_launch(void* const* d_in, const int* in_sizes, int n_in,
                              void* d_out, int out_size, void* d_ws, size_t ws_size,
                              hipStream_t stream) {
    const float* x = (const float*)d_in[0];   // [B,K,N] fp32
    const float* W = (const float*)d_in[1];   // [K,N]   fp32
    float* out = (float*)d_out;               // [B,K]   fp32

    const int blocks = out_size / (4 * ROWS_PER_WAVE);   // 262144/64 = 4096
    ginn_input_layer<<<blocks, 256, 0, stream>>>(x, W, out);
}